// Round 5
// baseline (403.392 us; speedup 1.0000x reference)
//
#include <hip/hip_runtime.h>

// Floyd-Steinberg dithering, BIT_WIDTH=1. 96 images of 512x512 fp32.
// Round 5: skew-packed input. pack_kernel pre-applies clip+(x+1)/2 and
// stores x01 in wavefront order: xp[img][w][P][lane][t] =
// x01[row 64w+lane][col 2P+t-2lane]. The dither kernel then reads ONE
// coalesced dwordx2 per lane per 2 steps (8 cache lines/load instead of
// 64 for the old scattered reads). Dither pipeline (R4-validated):
// 8 waves/block, wave w rows 64w+lane, skew c = T-2*lane, DPP wave_shr:1
// error hop, chunked LDS spin-flag handoff (lgkm-only, no vmcnt drains).
// Falls back to the R4 direct kernel if ws_size < 126 MB.
//
// Bit-exactness (validated R1-R4): op order matches reference, rintf =
// round-half-even, fp contract OFF in the recurrence; pack's pp() is the
// identical expression previously computed in-loop.

#define F_UL 0.0625f   // 1/16
#define F_U  0.3125f   // 5/16
#define F_UR 0.1875f   // 3/16
#define F_L  0.4375f   // 7/16

constexpr int WW    = 512;
constexpr int IMG   = WW * WW;
constexpr int NIMG  = 96;
constexpr int NW    = 8;      // waves per block
constexpr int BUFW  = 792;    // boundary region floats (+128 base offset)
constexpr int NCH   = 40;     // 16-step chunks (640 steps per wave)
constexpr int LAG   = 10;     // producer lead in chunks
constexpr int PPAIR = 320;    // step-pairs per (img,wave) region
// xp region: PPAIR * 64 lanes * 2 floats = PPAIR*128 floats (512B per pair)
constexpr size_t XP_FLOATS = (size_t)NIMG * NW * PPAIR * 128;
constexpr size_t XP_BYTES  = XP_FLOATS * 4;   // 125,829,120 B
constexpr size_t XP_SLACK  = 8192;            // prefetch overrun past last region

__device__ __forceinline__ float wave_shr1(float v, float fill) {
  int r = __builtin_amdgcn_update_dpp(__float_as_int(fill), __float_as_int(v),
                                      0x138 /*wave_shr:1*/, 0xF, 0xF, false);
  return __int_as_float(r);
}

__device__ __forceinline__ float pp(float xv) {   // x -> x01, ref op order
#pragma clang fp contract(off)
  float xc = fminf(fmaxf(xv, -1.0f), 1.0f);
  return (xc + 1.0f) * 0.5f;
}

// ---------------- pack: x -> skewed, preprocessed xp ----------------
__global__ __launch_bounds__(256)
void pack_kernel(const float* __restrict__ xin, float* __restrict__ xp) {
  const int img = blockIdx.x, w = blockIdx.y;
  const float* xb = xin + (size_t)img * IMG + (size_t)w * 64 * WW;
  float* ob = xp + ((size_t)(img * NW + w) * PPAIR) * 128;
  for (int flat = threadIdx.x; flat < PPAIR * 64; flat += 256) {
    const int P = flat >> 6, l = flat & 63;
    const int c = 2 * P - 2 * l;
    float a = xb[l * WW + (c & 511)];        // masked addr; invalid cols are
    float b = xb[l * WW + ((c + 1) & 511)];  // don't-care (en masked later)
    *(float2*)(ob + (size_t)flat * 2) = make_float2(pp(a), pp(b));
  }
}

// ---------------- main dither kernel (packed-x path) ----------------
__global__ __launch_bounds__(512, 1)
void dither_packed(const float* __restrict__ xp, float* __restrict__ yout) {
  __shared__ float bnd[(NW + 1) * BUFW];
  __shared__ int flags[NW];

  const int  tid  = threadIdx.x;
  const int  wave = tid >> 6;
  const int  lane = tid & 63;
  const int  img  = blockIdx.x;
  const bool l63  = (lane == 63);

  for (int i = tid; i < (NW + 1) * BUFW; i += 512) bnd[i] = 0.0f;
  if (tid < NW) flags[tid] = 0;
  __syncthreads();

  float* yrow = yout + (size_t)img * IMG + (size_t)(wave * 64 + lane) * WW;
  const float* xw = xp + ((size_t)(img * NW + wave) * PPAIR) * 128 + lane * 2;
  float* bufR = bnd + wave * BUFW;
  float* bufW = bnd + (wave + 1) * BUFW;
  const int c0 = -2 * lane;

  // ---- prime x pipeline: pairs 0..3 live, 4..7 mid, 8..11 in flight ----
  float2 A0 = *(const float2*)(xw + 0 * 128);
  float2 A1 = *(const float2*)(xw + 1 * 128);
  float2 A2 = *(const float2*)(xw + 2 * 128);
  float2 A3 = *(const float2*)(xw + 3 * 128);
  float2 m0 = *(const float2*)(xw + 4 * 128);
  float2 m1 = *(const float2*)(xw + 5 * 128);
  float2 m2 = *(const float2*)(xw + 6 * 128);
  float2 m3 = *(const float2*)(xw + 7 * 128);
  float2 f0 = *(const float2*)(xw + 8 * 128);
  float2 f1 = *(const float2*)(xw + 9 * 128);
  float2 f2 = *(const float2*)(xw + 10 * 128);
  float2 f3 = *(const float2*)(xw + 11 * 128);
  float xq0 = A0.x, xq1 = A0.y, xq2 = A1.x, xq3 = A1.y;
  float xq4 = A2.x, xq5 = A2.y, xq6 = A3.x, xq7 = A3.y;

  if (wave) {
    while (__hip_atomic_load(&flags[wave - 1], __ATOMIC_ACQUIRE,
                             __HIP_MEMORY_SCOPE_WORKGROUP) < LAG)
      __builtin_amdgcn_s_sleep(1);
  }

  float err = 0.0f, s2 = 0.0f;
  float s1 = (lane == 0) ? bufR[129] : 0.0f;
  float2 qa = *(const float2*)(bufR + 130);
  float2 qb = *(const float2*)(bufR + 132);
  float2 qc = *(const float2*)(bufR + 134);
  float2 qd = *(const float2*)(bufR + 136);
  float2 fa = *(const float2*)(bufR + 138);
  float2 fb = *(const float2*)(bufR + 140);
  float2 fc = *(const float2*)(bufR + 142);
  float2 fd = *(const float2*)(bufR + 144);

  auto step = [&](int c, float qv, float xv) -> float {
#pragma clang fp contract(off)
    float e_in = wave_shr1(err, qv);          // err[r-1][c+1]
    float t1   = F_UL * s2;
    float t2   = F_U  * s1;
    float t3   = F_UR * e_in;
    float u    = (t1 + t2) + t3;              // ref's left-to-right order
    float a1   = xv + u;                      // xv = x01 (pre-packed)
    float b    = F_L * err;
    float v    = a1 + b;
    float val  = fminf(fmaxf(v, 0.0f), 1.0f);
    float qn   = rintf(val);                  // round-half-even
    float e    = val - qn;
    float en   = ((unsigned)c < 512u) ? e : 0.0f;
    err = en; s2 = s1; s1 = e_in;
    return __builtin_fmaf(qn, 2.0f, -1.0f);   // {0,1} -> {-1,+1}, exact
  };

  auto iter8 = [&](int T) {
    const int cg = c0 + T;
    // x prefetch: pairs T/2+12..15 (consumed 3 iterations later)
    const float* lp = xw + (size_t)(T / 2 + 12) * 128;
    float2 n0 = *(const float2*)(lp + 0 * 128);
    float2 n1 = *(const float2*)(lp + 1 * 128);
    float2 n2 = *(const float2*)(lp + 2 * 128);
    float2 n3 = *(const float2*)(lp + 3 * 128);
    // boundary prefetch for iteration T+16 (cols T+18..T+25)
    float2 g0 = *(const float2*)(bufR + (T + 146));
    float2 g1 = *(const float2*)(bufR + (T + 148));
    float2 g2 = *(const float2*)(bufR + (T + 150));
    float2 g3 = *(const float2*)(bufR + (T + 152));

    float y0 = step(cg + 0, qa.x, xq0); float e0 = err;
    float y1 = step(cg + 1, qa.y, xq1); float e1 = err;
    float y2 = step(cg + 2, qb.x, xq2); float e2 = err;
    float y3 = step(cg + 3, qb.y, xq3); float e3 = err;
    float y4 = step(cg + 4, qc.x, xq4); float e4 = err;
    float y5 = step(cg + 5, qc.y, xq5); float e5 = err;
    float y6 = step(cg + 6, qd.x, xq6); float e6 = err;
    float y7 = step(cg + 7, qd.y, xq7); float e7 = err;

    if ((unsigned)(cg + 0) < 511u) *(float2*)(yrow + cg + 0) = make_float2(y0, y1);
    if ((unsigned)(cg + 2) < 511u) *(float2*)(yrow + cg + 2) = make_float2(y2, y3);
    if ((unsigned)(cg + 4) < 511u) *(float2*)(yrow + cg + 4) = make_float2(y4, y5);
    if ((unsigned)(cg + 6) < 511u) *(float2*)(yrow + cg + 6) = make_float2(y6, y7);

    if (l63) {  // boundary row for next wave; cg+129 >= 3, no clamp needed
      float* bw = bufW + (cg + 129);
      bw[0] = e0; bw[1] = e1; bw[2] = e2; bw[3] = e3;
      bw[4] = e4; bw[5] = e5; bw[6] = e6; bw[7] = e7;
    }

    xq0 = m0.x; xq1 = m0.y; xq2 = m1.x; xq3 = m1.y;
    xq4 = m2.x; xq5 = m2.y; xq6 = m3.x; xq7 = m3.y;
    m0 = f0; m1 = f1; m2 = f2; m3 = f3;
    f0 = n0; f1 = n1; f2 = n2; f3 = n3;
    qa = fa; qb = fb; qc = fc; qd = fd;
    fa = g0; fb = g1; fc = g2; fd = g3;
  };

  for (int j = 0; j < NCH; ++j) {
    if (wave) {
      int need = j + LAG; if (need > NCH) need = NCH;
      while (__hip_atomic_load(&flags[wave - 1], __ATOMIC_ACQUIRE,
                               __HIP_MEMORY_SCOPE_WORKGROUP) < need)
        __builtin_amdgcn_s_sleep(1);
    }
    iter8(16 * j);
    iter8(16 * j + 8);
    if (l63)
      __hip_atomic_store(&flags[wave], j + 1, __ATOMIC_RELEASE,
                         __HIP_MEMORY_SCOPE_WORKGROUP);
  }
}

// ---------------- fallback: R4 direct-x kernel (known-good) ----------------
__global__ __launch_bounds__(512, 1)
void dither_direct(const float* __restrict__ xin, float* __restrict__ yout) {
  __shared__ float bnd[(NW + 1) * BUFW];
  __shared__ int flags[NW];

  const int  tid  = threadIdx.x;
  const int  wave = tid >> 6;
  const int  lane = tid & 63;
  const int  img  = blockIdx.x;
  const bool l63  = (lane == 63);

  for (int i = tid; i < (NW + 1) * BUFW; i += 512) bnd[i] = 0.0f;
  if (tid < NW) flags[tid] = 0;
  __syncthreads();

  const int r = wave * 64 + lane;
  const float* xrow = xin + (size_t)img * IMG + (size_t)r * WW;
  float*       yrow = yout + (size_t)img * IMG + (size_t)r * WW;
  float* bufR = bnd + wave * BUFW;
  float* bufW = bnd + (wave + 1) * BUFW;
  const int c0 = -2 * lane;

  auto ldx = [&](int c) -> float2 { return *(const float2*)(xrow + (c & 511)); };

  float2 A0 = ldx(c0 + 0),  A1 = ldx(c0 + 2),  A2 = ldx(c0 + 4),  A3 = ldx(c0 + 6);
  float2 pB0 = ldx(c0 + 8),  pB1 = ldx(c0 + 10), pB2 = ldx(c0 + 12), pB3 = ldx(c0 + 14);
  float2 pC0 = ldx(c0 + 16), pC1 = ldx(c0 + 18), pC2 = ldx(c0 + 20), pC3 = ldx(c0 + 22);
  float xq0 = pp(A0.x), xq1 = pp(A0.y), xq2 = pp(A1.x), xq3 = pp(A1.y);
  float xq4 = pp(A2.x), xq5 = pp(A2.y), xq6 = pp(A3.x), xq7 = pp(A3.y);
  float2 pA0 = pB0, pA1 = pB1, pA2 = pB2, pA3 = pB3;
  pB0 = pC0; pB1 = pC1; pB2 = pC2; pB3 = pC3;

  if (wave) {
    while (__hip_atomic_load(&flags[wave - 1], __ATOMIC_ACQUIRE,
                             __HIP_MEMORY_SCOPE_WORKGROUP) < LAG)
      __builtin_amdgcn_s_sleep(1);
  }

  float err = 0.0f, s2 = 0.0f;
  float s1 = (lane == 0) ? bufR[129] : 0.0f;
  float2 qa = *(const float2*)(bufR + 130);
  float2 qb = *(const float2*)(bufR + 132);
  float2 qc = *(const float2*)(bufR + 134);
  float2 qd = *(const float2*)(bufR + 136);
  float2 fa = *(const float2*)(bufR + 138);
  float2 fb = *(const float2*)(bufR + 140);
  float2 fc = *(const float2*)(bufR + 142);
  float2 fd = *(const float2*)(bufR + 144);

  auto step = [&](int c, float qv, float xv) -> float {
#pragma clang fp contract(off)
    float e_in = wave_shr1(err, qv);
    float t1   = F_UL * s2;
    float t2   = F_U  * s1;
    float t3   = F_UR * e_in;
    float u    = (t1 + t2) + t3;
    float a1   = xv + u;
    float b    = F_L * err;
    float v    = a1 + b;
    float val  = fminf(fmaxf(v, 0.0f), 1.0f);
    float qn   = rintf(val);
    float e    = val - qn;
    float en   = ((unsigned)c < 512u) ? e : 0.0f;
    err = en; s2 = s1; s1 = e_in;
    return __builtin_fmaf(qn, 2.0f, -1.0f);
  };

  auto iter8 = [&](int T) {
    const int cg = c0 + T;
    float2 n0 = ldx(cg + 24), n1 = ldx(cg + 26), n2 = ldx(cg + 28), n3 = ldx(cg + 30);
    float2 g0 = *(const float2*)(bufR + (T + 146));
    float2 g1 = *(const float2*)(bufR + (T + 148));
    float2 g2 = *(const float2*)(bufR + (T + 150));
    float2 g3 = *(const float2*)(bufR + (T + 152));
    float w0 = pp(pA0.x), w1 = pp(pA0.y), w2 = pp(pA1.x), w3 = pp(pA1.y);
    float w4 = pp(pA2.x), w5 = pp(pA2.y), w6 = pp(pA3.x), w7 = pp(pA3.y);

    float y0 = step(cg + 0, qa.x, xq0); float e0 = err;
    float y1 = step(cg + 1, qa.y, xq1); float e1 = err;
    float y2 = step(cg + 2, qb.x, xq2); float e2 = err;
    float y3 = step(cg + 3, qb.y, xq3); float e3 = err;
    float y4 = step(cg + 4, qc.x, xq4); float e4 = err;
    float y5 = step(cg + 5, qc.y, xq5); float e5 = err;
    float y6 = step(cg + 6, qd.x, xq6); float e6 = err;
    float y7 = step(cg + 7, qd.y, xq7); float e7 = err;

    if ((unsigned)(cg + 0) < 511u) *(float2*)(yrow + cg + 0) = make_float2(y0, y1);
    if ((unsigned)(cg + 2) < 511u) *(float2*)(yrow + cg + 2) = make_float2(y2, y3);
    if ((unsigned)(cg + 4) < 511u) *(float2*)(yrow + cg + 4) = make_float2(y4, y5);
    if ((unsigned)(cg + 6) < 511u) *(float2*)(yrow + cg + 6) = make_float2(y6, y7);

    if (l63) {
      float* bw = bufW + (cg + 129);
      bw[0] = e0; bw[1] = e1; bw[2] = e2; bw[3] = e3;
      bw[4] = e4; bw[5] = e5; bw[6] = e6; bw[7] = e7;
    }

    xq0 = w0; xq1 = w1; xq2 = w2; xq3 = w3;
    xq4 = w4; xq5 = w5; xq6 = w6; xq7 = w7;
    pA0 = pB0; pA1 = pB1; pA2 = pB2; pA3 = pB3;
    pB0 = n0;  pB1 = n1;  pB2 = n2;  pB3 = n3;
    qa = fa; qb = fb; qc = fc; qd = fd;
    fa = g0; fb = g1; fc = g2; fd = g3;
  };

  for (int j = 0; j < NCH; ++j) {
    if (wave) {
      int need = j + LAG; if (need > NCH) need = NCH;
      while (__hip_atomic_load(&flags[wave - 1], __ATOMIC_ACQUIRE,
                               __HIP_MEMORY_SCOPE_WORKGROUP) < need)
        __builtin_amdgcn_s_sleep(1);
    }
    iter8(16 * j);
    iter8(16 * j + 8);
    if (l63)
      __hip_atomic_store(&flags[wave], j + 1, __ATOMIC_RELEASE,
                         __HIP_MEMORY_SCOPE_WORKGROUP);
  }
}

extern "C" void kernel_launch(void* const* d_in, const int* in_sizes, int n_in,
                              void* d_out, int out_size, void* d_ws, size_t ws_size,
                              hipStream_t stream) {
  const float* x = (const float*)d_in[0];
  float*       y = (float*)d_out;
  if (ws_size >= XP_BYTES + XP_SLACK) {
    float* xp = (float*)d_ws;
    pack_kernel<<<dim3(NIMG, NW), dim3(256), 0, stream>>>(x, xp);
    dither_packed<<<dim3(NIMG), dim3(512), 0, stream>>>(xp, y);
  } else {
    dither_direct<<<dim3(NIMG), dim3(512), 0, stream>>>(x, y);
  }
}

// Round 6
// 390.074 us; speedup vs baseline: 1.0341x; 1.0341x over previous
//
#include <hip/hip_runtime.h>

// Floyd-Steinberg dithering, BIT_WIDTH=1. 96 images of 512x512 fp32.
// Round 6:
//  (a) pack_kernel v2: LDS tile transpose. Coalesced float4 tile loads
//      (64x64), skewed emission from LDS (stride-65 pad, conflict-free),
//      contiguous float2 output writes. Was gather-bound (~190us), now
//      BW-bound.
//  (b) dither: replace workgroup-RELEASE flag store (which emitted
//      s_waitcnt vmcnt(0) every chunk, draining the x prefetch pipeline)
//      with s_waitcnt lgkmcnt(0) + RELAXED store. bufW/flags are LDS-only
//      and DS ops complete in order per wave, so this is sufficient.
//      Consumer spin likewise RELAXED + lgkmcnt barrier.
//  (c) x prefetch deepened 3 -> 4 iterations (32-step lead).
//
// Dither pipeline (R4/R5-validated): 8 waves/block, wave w owns rows
// 64w+lane, skew c = T - 2*lane, DPP wave_shr:1 error hop, chunked LDS
// spin-flag handoff. Bit-exactness (R1-R5): ref op order, rintf
// (round-half-even), fp contract OFF in the recurrence.

#define F_UL 0.0625f   // 1/16
#define F_U  0.3125f   // 5/16
#define F_UR 0.1875f   // 3/16
#define F_L  0.4375f   // 7/16

constexpr int WW    = 512;
constexpr int IMG   = WW * WW;
constexpr int NIMG  = 96;
constexpr int NW    = 8;      // waves per block
constexpr int BUFW  = 792;    // boundary region floats (+128 base offset)
constexpr int NCH   = 40;     // 16-step chunks (640 steps per wave)
constexpr int LAG   = 10;     // producer lead in chunks (min: 158/16 -> 10)
constexpr int PPAIR = 320;    // step-pairs per (img,wave) region
constexpr size_t XP_FLOATS = (size_t)NIMG * NW * PPAIR * 128;
constexpr size_t XP_BYTES  = XP_FLOATS * 4;   // 125,829,120 B
constexpr size_t XP_SLACK  = 8192;            // 4-deep prefetch overrun: 16 pairs*512B

__device__ __forceinline__ float wave_shr1(float v, float fill) {
  int r = __builtin_amdgcn_update_dpp(__float_as_int(fill), __float_as_int(v),
                                      0x138 /*wave_shr:1*/, 0xF, 0xF, false);
  return __int_as_float(r);
}

__device__ __forceinline__ float pp(float xv) {   // x -> x01, ref op order
#pragma clang fp contract(off)
  float xc = fminf(fmaxf(xv, -1.0f), 1.0f);
  return (xc + 1.0f) * 0.5f;
}

// ---------------- pack v2: LDS tile transpose ----------------
// grid (NIMG, NW, 8 col-tiles); block 256.
// Tile ct covers cols C..C+63 of the band's 64 rows. Pair (P, l) holds
// x01 at cols (2P-2l, 2P+1-2l) of row l; tile ct owns pairs where
// c = 2P-2l-C in [0,63], i.e. m = P - 32*ct in [l, l+31] -> m in [0,94].
// Pairs with 2P-2l < 0 or >= 512 are never written (consumed only by
// masked steps; 0xAA poison is finite and harmless).
__global__ __launch_bounds__(256)
void pack_kernel(const float* __restrict__ xin, float* __restrict__ xp) {
  __shared__ float tile[64 * 65];   // stride 65: conflict-free skewed reads
  const int img = blockIdx.x, w = blockIdx.y, ct = blockIdx.z;
  const int C   = ct * 64;
  const int tid = threadIdx.x;

  const float* xg = xin + (size_t)img * IMG + (size_t)w * 64 * WW;
  // load 64x64 tile, fully coalesced float4 (16 lanes per row)
  for (int k = 0; k < 4; ++k) {
    int flat = tid + 256 * k;            // 0..1023
    int row = flat >> 4, cq = flat & 15;
    float4 v = *(const float4*)(xg + row * WW + C + cq * 4);
    float* d = tile + row * 65 + cq * 4;
    d[0] = pp(v.x); d[1] = pp(v.y); d[2] = pp(v.z); d[3] = pp(v.w);
  }
  __syncthreads();

  float* ob = xp + ((size_t)(img * NW + w) * PPAIR + 32 * ct) * 128;
  const int l = tid & 63, mo = tid >> 6;
  for (int k = 0; k < 24; ++k) {
    int m = mo + 4 * k;                  // 0..95 (95 skipped)
    if (m <= 94 && l <= m && m <= l + 31) {
      int c = 2 * (m - l);               // 0..62
      float2 v = make_float2(tile[l * 65 + c], tile[l * 65 + c + 1]);
      *(float2*)(ob + (size_t)m * 128 + 2 * l) = v;   // contiguous across lanes
    }
  }
}

// ---------------- main dither kernel (packed-x path) ----------------
__global__ __launch_bounds__(512, 1)
void dither_packed(const float* __restrict__ xp, float* __restrict__ yout) {
  __shared__ float bnd[(NW + 1) * BUFW];
  __shared__ int flags[NW];

  const int  tid  = threadIdx.x;
  const int  wave = tid >> 6;
  const int  lane = tid & 63;
  const int  img  = blockIdx.x;
  const bool l63  = (lane == 63);

  for (int i = tid; i < (NW + 1) * BUFW; i += 512) bnd[i] = 0.0f;
  if (tid < NW) flags[tid] = 0;
  __syncthreads();

  float* yrow = yout + (size_t)img * IMG + (size_t)(wave * 64 + lane) * WW;
  const float* xw = xp + ((size_t)(img * NW + wave) * PPAIR) * 128 + lane * 2;
  float* bufR = bnd + wave * BUFW;
  float* bufW = bnd + (wave + 1) * BUFW;
  const int c0 = -2 * lane;

  // ---- prime x pipeline, 4 iterations deep (pairs 0..15) ----
  float2 A0 = *(const float2*)(xw + 0 * 128);
  float2 A1 = *(const float2*)(xw + 1 * 128);
  float2 A2 = *(const float2*)(xw + 2 * 128);
  float2 A3 = *(const float2*)(xw + 3 * 128);
  float2 m0 = *(const float2*)(xw + 4 * 128);
  float2 m1 = *(const float2*)(xw + 5 * 128);
  float2 m2 = *(const float2*)(xw + 6 * 128);
  float2 m3 = *(const float2*)(xw + 7 * 128);
  float2 f0 = *(const float2*)(xw + 8 * 128);
  float2 f1 = *(const float2*)(xw + 9 * 128);
  float2 f2 = *(const float2*)(xw + 10 * 128);
  float2 f3 = *(const float2*)(xw + 11 * 128);
  float2 g0 = *(const float2*)(xw + 12 * 128);
  float2 g1 = *(const float2*)(xw + 13 * 128);
  float2 g2 = *(const float2*)(xw + 14 * 128);
  float2 g3 = *(const float2*)(xw + 15 * 128);
  float xq0 = A0.x, xq1 = A0.y, xq2 = A1.x, xq3 = A1.y;
  float xq4 = A2.x, xq5 = A2.y, xq6 = A3.x, xq7 = A3.y;

  if (wave) {
    while (__hip_atomic_load(&flags[wave - 1], __ATOMIC_RELAXED,
                             __HIP_MEMORY_SCOPE_WORKGROUP) < LAG)
      __builtin_amdgcn_s_sleep(1);
    __asm__ volatile("s_waitcnt lgkmcnt(0)" ::: "memory");
  }

  float err = 0.0f, s2 = 0.0f;
  float s1 = (lane == 0) ? bufR[129] : 0.0f;
  float2 qa = *(const float2*)(bufR + 130);
  float2 qb = *(const float2*)(bufR + 132);
  float2 qc = *(const float2*)(bufR + 134);
  float2 qd = *(const float2*)(bufR + 136);
  float2 fa = *(const float2*)(bufR + 138);
  float2 fb = *(const float2*)(bufR + 140);
  float2 fc = *(const float2*)(bufR + 142);
  float2 fd = *(const float2*)(bufR + 144);

  auto step = [&](int c, float qv, float xv) -> float {
#pragma clang fp contract(off)
    float e_in = wave_shr1(err, qv);          // err[r-1][c+1]
    float t1   = F_UL * s2;
    float t2   = F_U  * s1;
    float t3   = F_UR * e_in;
    float u    = (t1 + t2) + t3;              // ref's left-to-right order
    float a1   = xv + u;                      // xv = x01 (pre-packed)
    float b    = F_L * err;
    float v    = a1 + b;
    float val  = fminf(fmaxf(v, 0.0f), 1.0f);
    float qn   = rintf(val);                  // round-half-even
    float e    = val - qn;
    float en   = ((unsigned)c < 512u) ? e : 0.0f;
    err = en; s2 = s1; s1 = e_in;
    return __builtin_fmaf(qn, 2.0f, -1.0f);   // {0,1} -> {-1,+1}, exact
  };

  auto iter8 = [&](int T) {
    const int cg = c0 + T;
    // x prefetch: pairs T/2+16..19 (consumed 4 iterations later)
    const float* lp = xw + (size_t)(T / 2 + 16) * 128;
    float2 n0 = *(const float2*)(lp + 0 * 128);
    float2 n1 = *(const float2*)(lp + 1 * 128);
    float2 n2 = *(const float2*)(lp + 2 * 128);
    float2 n3 = *(const float2*)(lp + 3 * 128);
    // boundary prefetch for iteration T+16 (cols T+17..T+24)
    float2 h0 = *(const float2*)(bufR + (T + 146));
    float2 h1 = *(const float2*)(bufR + (T + 148));
    float2 h2 = *(const float2*)(bufR + (T + 150));
    float2 h3 = *(const float2*)(bufR + (T + 152));

    float y0 = step(cg + 0, qa.x, xq0); float e0 = err;
    float y1 = step(cg + 1, qa.y, xq1); float e1 = err;
    float y2 = step(cg + 2, qb.x, xq2); float e2 = err;
    float y3 = step(cg + 3, qb.y, xq3); float e3 = err;
    float y4 = step(cg + 4, qc.x, xq4); float e4 = err;
    float y5 = step(cg + 5, qc.y, xq5); float e5 = err;
    float y6 = step(cg + 6, qd.x, xq6); float e6 = err;
    float y7 = step(cg + 7, qd.y, xq7); float e7 = err;

    if ((unsigned)(cg + 0) < 511u) *(float2*)(yrow + cg + 0) = make_float2(y0, y1);
    if ((unsigned)(cg + 2) < 511u) *(float2*)(yrow + cg + 2) = make_float2(y2, y3);
    if ((unsigned)(cg + 4) < 511u) *(float2*)(yrow + cg + 4) = make_float2(y4, y5);
    if ((unsigned)(cg + 6) < 511u) *(float2*)(yrow + cg + 6) = make_float2(y6, y7);

    if (l63) {  // boundary row for next wave; cg+129 >= 3, no clamp needed
      float* bw = bufW + (cg + 129);
      bw[0] = e0; bw[1] = e1; bw[2] = e2; bw[3] = e3;
      bw[4] = e4; bw[5] = e5; bw[6] = e6; bw[7] = e7;
    }

    xq0 = m0.x; xq1 = m0.y; xq2 = m1.x; xq3 = m1.y;
    xq4 = m2.x; xq5 = m2.y; xq6 = m3.x; xq7 = m3.y;
    m0 = f0; m1 = f1; m2 = f2; m3 = f3;
    f0 = g0; f1 = g1; f2 = g2; f3 = g3;
    g0 = n0; g1 = n1; g2 = n2; g3 = n3;
    qa = fa; qb = fb; qc = fc; qd = fd;
    fa = h0; fb = h1; fc = h2; fd = h3;
  };

  for (int j = 0; j < NCH; ++j) {
    if (wave) {
      int need = j + LAG; if (need > NCH) need = NCH;
      while (__hip_atomic_load(&flags[wave - 1], __ATOMIC_RELAXED,
                               __HIP_MEMORY_SCOPE_WORKGROUP) < need)
        __builtin_amdgcn_s_sleep(1);
      __asm__ volatile("s_waitcnt lgkmcnt(0)" ::: "memory");
    }
    iter8(16 * j);
    iter8(16 * j + 8);
    if (l63) {
      // bufW writes are LDS-only; DS ops complete in order per wave, so
      // lgkmcnt(0) + RELAXED store publishes without a vmcnt(0) drain.
      __asm__ volatile("s_waitcnt lgkmcnt(0)" ::: "memory");
      __hip_atomic_store(&flags[wave], j + 1, __ATOMIC_RELAXED,
                         __HIP_MEMORY_SCOPE_WORKGROUP);
    }
  }
}

// ---------------- fallback: R4 direct-x kernel (known-good) ----------------
__global__ __launch_bounds__(512, 1)
void dither_direct(const float* __restrict__ xin, float* __restrict__ yout) {
  __shared__ float bnd[(NW + 1) * BUFW];
  __shared__ int flags[NW];

  const int  tid  = threadIdx.x;
  const int  wave = tid >> 6;
  const int  lane = tid & 63;
  const int  img  = blockIdx.x;
  const bool l63  = (lane == 63);

  for (int i = tid; i < (NW + 1) * BUFW; i += 512) bnd[i] = 0.0f;
  if (tid < NW) flags[tid] = 0;
  __syncthreads();

  const int r = wave * 64 + lane;
  const float* xrow = xin + (size_t)img * IMG + (size_t)r * WW;
  float*       yrow = yout + (size_t)img * IMG + (size_t)r * WW;
  float* bufR = bnd + wave * BUFW;
  float* bufW = bnd + (wave + 1) * BUFW;
  const int c0 = -2 * lane;

  auto ldx = [&](int c) -> float2 { return *(const float2*)(xrow + (c & 511)); };

  float2 A0 = ldx(c0 + 0),  A1 = ldx(c0 + 2),  A2 = ldx(c0 + 4),  A3 = ldx(c0 + 6);
  float2 pB0 = ldx(c0 + 8),  pB1 = ldx(c0 + 10), pB2 = ldx(c0 + 12), pB3 = ldx(c0 + 14);
  float2 pC0 = ldx(c0 + 16), pC1 = ldx(c0 + 18), pC2 = ldx(c0 + 20), pC3 = ldx(c0 + 22);
  float xq0 = pp(A0.x), xq1 = pp(A0.y), xq2 = pp(A1.x), xq3 = pp(A1.y);
  float xq4 = pp(A2.x), xq5 = pp(A2.y), xq6 = pp(A3.x), xq7 = pp(A3.y);
  float2 pA0 = pB0, pA1 = pB1, pA2 = pB2, pA3 = pB3;
  pB0 = pC0; pB1 = pC1; pB2 = pC2; pB3 = pC3;

  if (wave) {
    while (__hip_atomic_load(&flags[wave - 1], __ATOMIC_RELAXED,
                             __HIP_MEMORY_SCOPE_WORKGROUP) < LAG)
      __builtin_amdgcn_s_sleep(1);
    __asm__ volatile("s_waitcnt lgkmcnt(0)" ::: "memory");
  }

  float err = 0.0f, s2 = 0.0f;
  float s1 = (lane == 0) ? bufR[129] : 0.0f;
  float2 qa = *(const float2*)(bufR + 130);
  float2 qb = *(const float2*)(bufR + 132);
  float2 qc = *(const float2*)(bufR + 134);
  float2 qd = *(const float2*)(bufR + 136);
  float2 fa = *(const float2*)(bufR + 138);
  float2 fb = *(const float2*)(bufR + 140);
  float2 fc = *(const float2*)(bufR + 142);
  float2 fd = *(const float2*)(bufR + 144);

  auto step = [&](int c, float qv, float xv) -> float {
#pragma clang fp contract(off)
    float e_in = wave_shr1(err, qv);
    float t1   = F_UL * s2;
    float t2   = F_U  * s1;
    float t3   = F_UR * e_in;
    float u    = (t1 + t2) + t3;
    float a1   = xv + u;
    float b    = F_L * err;
    float v    = a1 + b;
    float val  = fminf(fmaxf(v, 0.0f), 1.0f);
    float qn   = rintf(val);
    float e    = val - qn;
    float en   = ((unsigned)c < 512u) ? e : 0.0f;
    err = en; s2 = s1; s1 = e_in;
    return __builtin_fmaf(qn, 2.0f, -1.0f);
  };

  auto iter8 = [&](int T) {
    const int cg = c0 + T;
    float2 n0 = ldx(cg + 24), n1 = ldx(cg + 26), n2 = ldx(cg + 28), n3 = ldx(cg + 30);
    float2 h0 = *(const float2*)(bufR + (T + 146));
    float2 h1 = *(const float2*)(bufR + (T + 148));
    float2 h2 = *(const float2*)(bufR + (T + 150));
    float2 h3 = *(const float2*)(bufR + (T + 152));
    float w0 = pp(pA0.x), w1 = pp(pA0.y), w2 = pp(pA1.x), w3 = pp(pA1.y);
    float w4 = pp(pA2.x), w5 = pp(pA2.y), w6 = pp(pA3.x), w7 = pp(pA3.y);

    float y0 = step(cg + 0, qa.x, xq0); float e0 = err;
    float y1 = step(cg + 1, qa.y, xq1); float e1 = err;
    float y2 = step(cg + 2, qb.x, xq2); float e2 = err;
    float y3 = step(cg + 3, qb.y, xq3); float e3 = err;
    float y4 = step(cg + 4, qc.x, xq4); float e4 = err;
    float y5 = step(cg + 5, qc.y, xq5); float e5 = err;
    float y6 = step(cg + 6, qd.x, xq6); float e6 = err;
    float y7 = step(cg + 7, qd.y, xq7); float e7 = err;

    if ((unsigned)(cg + 0) < 511u) *(float2*)(yrow + cg + 0) = make_float2(y0, y1);
    if ((unsigned)(cg + 2) < 511u) *(float2*)(yrow + cg + 2) = make_float2(y2, y3);
    if ((unsigned)(cg + 4) < 511u) *(float2*)(yrow + cg + 4) = make_float2(y4, y5);
    if ((unsigned)(cg + 6) < 511u) *(float2*)(yrow + cg + 6) = make_float2(y6, y7);

    if (l63) {
      float* bw = bufW + (cg + 129);
      bw[0] = e0; bw[1] = e1; bw[2] = e2; bw[3] = e3;
      bw[4] = e4; bw[5] = e5; bw[6] = e6; bw[7] = e7;
    }

    xq0 = w0; xq1 = w1; xq2 = w2; xq3 = w3;
    xq4 = w4; xq5 = w5; xq6 = w6; xq7 = w7;
    pA0 = pB0; pA1 = pB1; pA2 = pB2; pA3 = pB3;
    pB0 = n0;  pB1 = n1;  pB2 = n2;  pB3 = n3;
    qa = fa; qb = fb; qc = fc; qd = fd;
    fa = h0; fb = h1; fc = h2; fd = h3;
  };

  for (int j = 0; j < NCH; ++j) {
    if (wave) {
      int need = j + LAG; if (need > NCH) need = NCH;
      while (__hip_atomic_load(&flags[wave - 1], __ATOMIC_RELAXED,
                               __HIP_MEMORY_SCOPE_WORKGROUP) < need)
        __builtin_amdgcn_s_sleep(1);
      __asm__ volatile("s_waitcnt lgkmcnt(0)" ::: "memory");
    }
    iter8(16 * j);
    iter8(16 * j + 8);
    if (l63) {
      __asm__ volatile("s_waitcnt lgkmcnt(0)" ::: "memory");
      __hip_atomic_store(&flags[wave], j + 1, __ATOMIC_RELAXED,
                         __HIP_MEMORY_SCOPE_WORKGROUP);
    }
  }
}

extern "C" void kernel_launch(void* const* d_in, const int* in_sizes, int n_in,
                              void* d_out, int out_size, void* d_ws, size_t ws_size,
                              hipStream_t stream) {
  const float* x = (const float*)d_in[0];
  float*       y = (float*)d_out;
  if (ws_size >= XP_BYTES + XP_SLACK) {
    float* xp = (float*)d_ws;
    pack_kernel<<<dim3(NIMG, NW, 8), dim3(256), 0, stream>>>(x, xp);
    dither_packed<<<dim3(NIMG), dim3(512), 0, stream>>>(xp, y);
  } else {
    dither_direct<<<dim3(NIMG), dim3(512), 0, stream>>>(x, y);
  }
}

// Round 7
// 330.322 us; speedup vs baseline: 1.2212x; 1.1809x over previous
//
#include <hip/hip_runtime.h>

// Floyd-Steinberg dithering, BIT_WIDTH=1. 96 images of 512x512 fp32.
// Round 7: fully-coalesced memory on every hot path.
//   pack_kernel : x -> skewed x01 pairs (LDS tile transpose, 8-iter emission)
//   dither_packed: 8-wave wavefront recurrence; y emitted as BITS (1 bit/px)
//                  into a 3.9 MB packed buffer -- one 512B coalesced store
//                  per wave per 64 steps. No scattered global traffic left.
//   unpack_kernel: bits -> ±1.0f, coalesced 100 MB write.
// Dither pipeline (R4-R6 validated): wave w owns rows 64w+lane, skew
// c = T-2*lane, DPP wave_shr:1 error hop, chunked LDS spin-flag handoff
// (RELAXED + lgkmcnt barrier; DS ops are in-order per wave).
// Bit-exactness (R1-R6): ref op order, rintf (round-half-even), contract OFF.

#define F_UL 0.0625f   // 1/16
#define F_U  0.3125f   // 5/16
#define F_UR 0.1875f   // 3/16
#define F_L  0.4375f   // 7/16

constexpr int WW    = 512;
constexpr int IMG   = WW * WW;
constexpr int NIMG  = 96;
constexpr int NW    = 8;      // waves per block
constexpr int BUFW  = 792;    // boundary region floats (+128 base offset)
constexpr int NCH   = 40;     // 16-step chunks (640 steps per wave)
constexpr int LAG   = 10;     // producer lead in chunks
constexpr int PPAIR = 320;    // step-pairs per (img,wave) region
constexpr size_t XP_FLOATS = (size_t)NIMG * NW * PPAIR * 128;
constexpr size_t XP_BYTES  = XP_FLOATS * 4;        // 125,829,120 B
constexpr size_t XP_SLACK  = 8192;                 // prefetch overrun (16 pairs)
constexpr size_t XP_OFF    = 4u * 1024 * 1024;     // xp after yb region
constexpr size_t WS_NEED   = XP_OFF + XP_BYTES + XP_SLACK;
// yb: per (img,wave): 10 windows x 64 lanes x 8B = 5120 B; total 3.93 MB (+pad)

__device__ __forceinline__ float wave_shr1(float v, float fill) {
  int r = __builtin_amdgcn_update_dpp(__float_as_int(fill), __float_as_int(v),
                                      0x138 /*wave_shr:1*/, 0xF, 0xF, false);
  return __int_as_float(r);
}

__device__ __forceinline__ float pp(float xv) {   // x -> x01, ref op order
#pragma clang fp contract(off)
  float xc = fminf(fmaxf(xv, -1.0f), 1.0f);
  return (xc + 1.0f) * 0.5f;
}

// ---------------- pack: x -> skewed, preprocessed xp ----------------
__global__ __launch_bounds__(256)
void pack_kernel(const float* __restrict__ xin, float* __restrict__ xp) {
  __shared__ float tile[64 * 65];
  const int img = blockIdx.x, w = blockIdx.y, ct = blockIdx.z;
  const int C   = ct * 64;
  const int tid = threadIdx.x;

  const float* xg = xin + (size_t)img * IMG + (size_t)w * 64 * WW;
  for (int k = 0; k < 4; ++k) {
    int flat = tid + 256 * k;
    int row = flat >> 4, cq = flat & 15;
    float4 v = *(const float4*)(xg + row * WW + C + cq * 4);
    float* d = tile + row * 65 + cq * 4;
    d[0] = pp(v.x); d[1] = pp(v.y); d[2] = pp(v.z); d[3] = pp(v.w);
  }
  __syncthreads();

  float* ob = xp + ((size_t)(img * NW + w) * PPAIR + 32 * ct) * 128;
  const int l = tid & 63, mo = tid >> 6;
  const int kst = (l - mo + 3) >> 2;       // ceil((l-mo)/4); exactly 8 active m's
  for (int k = 0; k < 8; ++k) {
    int m = mo + 4 * (kst + k);            // m in [l, l+31], stride 4
    if (m <= 94) {
      int c = 2 * (m - l);                 // 0..62
      float2 v = make_float2(tile[l * 65 + c], tile[l * 65 + c + 1]);
      *(float2*)(ob + (size_t)m * 128 + 2 * l) = v;
    }
  }
}

// ---------------- main dither kernel: packed x in, packed bits out ----------
__global__ __launch_bounds__(512, 1)
void dither_packed(const float* __restrict__ xp, uint2* __restrict__ yb) {
  __shared__ float bnd[(NW + 1) * BUFW];
  __shared__ int flags[NW];

  const int  tid  = threadIdx.x;
  const int  wave = tid >> 6;
  const int  lane = tid & 63;
  const int  img  = blockIdx.x;
  const bool l63  = (lane == 63);

  for (int i = tid; i < (NW + 1) * BUFW; i += 512) bnd[i] = 0.0f;
  if (tid < NW) flags[tid] = 0;
  __syncthreads();

  uint2* ybw = yb + (size_t)(img * NW + wave) * (10 * 64);  // 10 windows x 64 lanes
  const float* xw = xp + ((size_t)(img * NW + wave) * PPAIR) * 128 + lane * 2;
  float* bufR = bnd + wave * BUFW;
  float* bufW = bnd + (wave + 1) * BUFW;
  const int c0 = -2 * lane;

  // ---- prime x pipeline, 4 iterations deep (pairs 0..15) ----
  float2 A0 = *(const float2*)(xw + 0 * 128);
  float2 A1 = *(const float2*)(xw + 1 * 128);
  float2 A2 = *(const float2*)(xw + 2 * 128);
  float2 A3 = *(const float2*)(xw + 3 * 128);
  float2 m0 = *(const float2*)(xw + 4 * 128);
  float2 m1 = *(const float2*)(xw + 5 * 128);
  float2 m2 = *(const float2*)(xw + 6 * 128);
  float2 m3 = *(const float2*)(xw + 7 * 128);
  float2 f0 = *(const float2*)(xw + 8 * 128);
  float2 f1 = *(const float2*)(xw + 9 * 128);
  float2 f2 = *(const float2*)(xw + 10 * 128);
  float2 f3 = *(const float2*)(xw + 11 * 128);
  float2 g0 = *(const float2*)(xw + 12 * 128);
  float2 g1 = *(const float2*)(xw + 13 * 128);
  float2 g2 = *(const float2*)(xw + 14 * 128);
  float2 g3 = *(const float2*)(xw + 15 * 128);
  float xq0 = A0.x, xq1 = A0.y, xq2 = A1.x, xq3 = A1.y;
  float xq4 = A2.x, xq5 = A2.y, xq6 = A3.x, xq7 = A3.y;

  if (wave) {
    while (__hip_atomic_load(&flags[wave - 1], __ATOMIC_RELAXED,
                             __HIP_MEMORY_SCOPE_WORKGROUP) < LAG)
      __builtin_amdgcn_s_sleep(1);
    __asm__ volatile("s_waitcnt lgkmcnt(0)" ::: "memory");
  }

  float err = 0.0f, s2 = 0.0f;
  float s1 = (lane == 0) ? bufR[129] : 0.0f;
  float2 qa = *(const float2*)(bufR + 130);
  float2 qb = *(const float2*)(bufR + 132);
  float2 qc = *(const float2*)(bufR + 134);
  float2 qd = *(const float2*)(bufR + 136);
  float2 fa = *(const float2*)(bufR + 138);
  float2 fb = *(const float2*)(bufR + 140);
  float2 fc = *(const float2*)(bufR + 142);
  float2 fd = *(const float2*)(bufR + 144);

  unsigned accLo = 0u, accHi = 0u;   // 64-step bit window

  auto step = [&](int c, float qv, float xv) -> float {
#pragma clang fp contract(off)
    float e_in = wave_shr1(err, qv);          // err[r-1][c+1]
    float t1   = F_UL * s2;
    float t2   = F_U  * s1;
    float t3   = F_UR * e_in;
    float u    = (t1 + t2) + t3;              // ref's left-to-right order
    float a1   = xv + u;                      // xv = x01 (pre-packed)
    float b    = F_L * err;
    float v    = a1 + b;
    float val  = fminf(fmaxf(v, 0.0f), 1.0f);
    float qn   = rintf(val);                  // round-half-even
    float e    = val - qn;
    float en   = ((unsigned)c < 512u) ? e : 0.0f;
    err = en; s2 = s1; s1 = e_in;
    return qn;                                // 0.0f or 1.0f
  };

  auto iter8 = [&](int T, unsigned& acc) {    // acc statically bound per call site
    const int cg  = c0 + T;
    const int bsh = T & 31;                   // window-half bit offset
    // x prefetch: pairs T/2+16..19 (consumed 4 iterations later)
    const float* lp = xw + (size_t)(T / 2 + 16) * 128;
    float2 n0 = *(const float2*)(lp + 0 * 128);
    float2 n1 = *(const float2*)(lp + 1 * 128);
    float2 n2 = *(const float2*)(lp + 2 * 128);
    float2 n3 = *(const float2*)(lp + 3 * 128);
    // boundary prefetch for iteration T+16
    float2 h0 = *(const float2*)(bufR + (T + 146));
    float2 h1 = *(const float2*)(bufR + (T + 148));
    float2 h2 = *(const float2*)(bufR + (T + 150));
    float2 h3 = *(const float2*)(bufR + (T + 152));

    float p0 = step(cg + 0, qa.x, xq0); float e0 = err;
    float p1 = step(cg + 1, qa.y, xq1); float e1 = err;
    float p2 = step(cg + 2, qb.x, xq2); float e2 = err;
    float p3 = step(cg + 3, qb.y, xq3); float e3 = err;
    float p4 = step(cg + 4, qc.x, xq4); float e4 = err;
    float p5 = step(cg + 5, qc.y, xq5); float e5 = err;
    float p6 = step(cg + 6, qd.x, xq6); float e6 = err;
    float p7 = step(cg + 7, qd.y, xq7); float e7 = err;

    // bit = exponent bit 29 of qn (1.0f -> 1, 0.0f -> 0); off-chain
    acc |= ((__float_as_uint(p0) >> 29) & 1u) << (bsh + 0);
    acc |= ((__float_as_uint(p1) >> 29) & 1u) << (bsh + 1);
    acc |= ((__float_as_uint(p2) >> 29) & 1u) << (bsh + 2);
    acc |= ((__float_as_uint(p3) >> 29) & 1u) << (bsh + 3);
    acc |= ((__float_as_uint(p4) >> 29) & 1u) << (bsh + 4);
    acc |= ((__float_as_uint(p5) >> 29) & 1u) << (bsh + 5);
    acc |= ((__float_as_uint(p6) >> 29) & 1u) << (bsh + 6);
    acc |= ((__float_as_uint(p7) >> 29) & 1u) << (bsh + 7);

    if (l63) {  // boundary row for next wave; cg+129 >= 3, no clamp needed
      float* bw = bufW + (cg + 129);
      bw[0] = e0; bw[1] = e1; bw[2] = e2; bw[3] = e3;
      bw[4] = e4; bw[5] = e5; bw[6] = e6; bw[7] = e7;
    }

    xq0 = m0.x; xq1 = m0.y; xq2 = m1.x; xq3 = m1.y;
    xq4 = m2.x; xq5 = m2.y; xq6 = m3.x; xq7 = m3.y;
    m0 = f0; m1 = f1; m2 = f2; m3 = f3;
    f0 = g0; f1 = g1; f2 = g2; f3 = g3;
    g0 = n0; g1 = n1; g2 = n2; g3 = n3;
    qa = fa; qb = fb; qc = fc; qd = fd;
    fa = h0; fb = h1; fc = h2; fd = h3;
  };

  for (int j = 0; j < NCH; ++j) {
    if (wave) {
      int need = j + LAG; if (need > NCH) need = NCH;
      while (__hip_atomic_load(&flags[wave - 1], __ATOMIC_RELAXED,
                               __HIP_MEMORY_SCOPE_WORKGROUP) < need)
        __builtin_amdgcn_s_sleep(1);
      __asm__ volatile("s_waitcnt lgkmcnt(0)" ::: "memory");
    }
    if (j & 2) { iter8(16 * j, accHi); iter8(16 * j + 8, accHi); }
    else       { iter8(16 * j, accLo); iter8(16 * j + 8, accLo); }
    if ((j & 3) == 3) {                      // 64-step window complete
      ybw[(j >> 2) * 64 + lane] = make_uint2(accLo, accHi);
      accLo = 0u; accHi = 0u;
    }
    if (l63) {
      __asm__ volatile("s_waitcnt lgkmcnt(0)" ::: "memory");
      __hip_atomic_store(&flags[wave], j + 1, __ATOMIC_RELAXED,
                         __HIP_MEMORY_SCOPE_WORKGROUP);
    }
  }
}

// ---------------- unpack: bits -> ±1.0f, coalesced ----------------
__global__ __launch_bounds__(256)
void unpack_kernel(const unsigned long long* __restrict__ yb,
                   float* __restrict__ yout) {
  const int img = blockIdx.x, w = blockIdx.y;
  const int wv = threadIdx.x >> 6, lane = threadIdx.x & 63;
  const unsigned long long* ybr = yb + (size_t)(img * NW + w) * 640;
  float* yb0 = yout + (size_t)img * IMG + (size_t)w * 64 * WW;

  for (int rr = 0; rr < 16; ++rr) {
    const int r  = wv * 16 + rr;              // row within band (= dither lane)
    const int t0 = 8 * lane + 2 * r;          // first bit index (cols 8*lane..)
    const int t64 = t0 >> 6, sh = t0 & 63;    // sh even, <= 62
    unsigned long long w1 = ybr[(size_t)t64 * 64 + r];
    unsigned long long w2 = ybr[(size_t)(t64 + 1) * 64 + r];  // pad-covered
    unsigned bits = (unsigned)((w1 >> sh) | ((w2 << 1) << (63 - sh)));
    float* orow = yb0 + (size_t)r * WW + 8 * lane;
    float4 v0, v1;
    v0.x = (bits & 1u)   ? 1.0f : -1.0f;
    v0.y = (bits & 2u)   ? 1.0f : -1.0f;
    v0.z = (bits & 4u)   ? 1.0f : -1.0f;
    v0.w = (bits & 8u)   ? 1.0f : -1.0f;
    v1.x = (bits & 16u)  ? 1.0f : -1.0f;
    v1.y = (bits & 32u)  ? 1.0f : -1.0f;
    v1.z = (bits & 64u)  ? 1.0f : -1.0f;
    v1.w = (bits & 128u) ? 1.0f : -1.0f;
    *(float4*)(orow)     = v0;
    *(float4*)(orow + 4) = v1;
  }
}

// ---------------- fallback: R4/R6 direct-x kernel (known-good) --------------
__global__ __launch_bounds__(512, 1)
void dither_direct(const float* __restrict__ xin, float* __restrict__ yout) {
  __shared__ float bnd[(NW + 1) * BUFW];
  __shared__ int flags[NW];

  const int  tid  = threadIdx.x;
  const int  wave = tid >> 6;
  const int  lane = tid & 63;
  const int  img  = blockIdx.x;
  const bool l63  = (lane == 63);

  for (int i = tid; i < (NW + 1) * BUFW; i += 512) bnd[i] = 0.0f;
  if (tid < NW) flags[tid] = 0;
  __syncthreads();

  const int r = wave * 64 + lane;
  const float* xrow = xin + (size_t)img * IMG + (size_t)r * WW;
  float*       yrow = yout + (size_t)img * IMG + (size_t)r * WW;
  float* bufR = bnd + wave * BUFW;
  float* bufW = bnd + (wave + 1) * BUFW;
  const int c0 = -2 * lane;

  auto ldx = [&](int c) -> float2 { return *(const float2*)(xrow + (c & 511)); };

  float2 A0 = ldx(c0 + 0),  A1 = ldx(c0 + 2),  A2 = ldx(c0 + 4),  A3 = ldx(c0 + 6);
  float2 pB0 = ldx(c0 + 8),  pB1 = ldx(c0 + 10), pB2 = ldx(c0 + 12), pB3 = ldx(c0 + 14);
  float2 pC0 = ldx(c0 + 16), pC1 = ldx(c0 + 18), pC2 = ldx(c0 + 20), pC3 = ldx(c0 + 22);
  float xq0 = pp(A0.x), xq1 = pp(A0.y), xq2 = pp(A1.x), xq3 = pp(A1.y);
  float xq4 = pp(A2.x), xq5 = pp(A2.y), xq6 = pp(A3.x), xq7 = pp(A3.y);
  float2 pA0 = pB0, pA1 = pB1, pA2 = pB2, pA3 = pB3;
  pB0 = pC0; pB1 = pC1; pB2 = pC2; pB3 = pC3;

  if (wave) {
    while (__hip_atomic_load(&flags[wave - 1], __ATOMIC_RELAXED,
                             __HIP_MEMORY_SCOPE_WORKGROUP) < LAG)
      __builtin_amdgcn_s_sleep(1);
    __asm__ volatile("s_waitcnt lgkmcnt(0)" ::: "memory");
  }

  float err = 0.0f, s2 = 0.0f;
  float s1 = (lane == 0) ? bufR[129] : 0.0f;
  float2 qa = *(const float2*)(bufR + 130);
  float2 qb = *(const float2*)(bufR + 132);
  float2 qc = *(const float2*)(bufR + 134);
  float2 qd = *(const float2*)(bufR + 136);
  float2 fa = *(const float2*)(bufR + 138);
  float2 fb = *(const float2*)(bufR + 140);
  float2 fc = *(const float2*)(bufR + 142);
  float2 fd = *(const float2*)(bufR + 144);

  auto step = [&](int c, float qv, float xv) -> float {
#pragma clang fp contract(off)
    float e_in = wave_shr1(err, qv);
    float t1   = F_UL * s2;
    float t2   = F_U  * s1;
    float t3   = F_UR * e_in;
    float u    = (t1 + t2) + t3;
    float a1   = xv + u;
    float b    = F_L * err;
    float v    = a1 + b;
    float val  = fminf(fmaxf(v, 0.0f), 1.0f);
    float qn   = rintf(val);
    float e    = val - qn;
    float en   = ((unsigned)c < 512u) ? e : 0.0f;
    err = en; s2 = s1; s1 = e_in;
    return __builtin_fmaf(qn, 2.0f, -1.0f);
  };

  auto iter8 = [&](int T) {
    const int cg = c0 + T;
    float2 n0 = ldx(cg + 24), n1 = ldx(cg + 26), n2 = ldx(cg + 28), n3 = ldx(cg + 30);
    float2 h0 = *(const float2*)(bufR + (T + 146));
    float2 h1 = *(const float2*)(bufR + (T + 148));
    float2 h2 = *(const float2*)(bufR + (T + 150));
    float2 h3 = *(const float2*)(bufR + (T + 152));
    float w0 = pp(pA0.x), w1 = pp(pA0.y), w2 = pp(pA1.x), w3 = pp(pA1.y);
    float w4 = pp(pA2.x), w5 = pp(pA2.y), w6 = pp(pA3.x), w7 = pp(pA3.y);

    float y0 = step(cg + 0, qa.x, xq0); float e0 = err;
    float y1 = step(cg + 1, qa.y, xq1); float e1 = err;
    float y2 = step(cg + 2, qb.x, xq2); float e2 = err;
    float y3 = step(cg + 3, qb.y, xq3); float e3 = err;
    float y4 = step(cg + 4, qc.x, xq4); float e4 = err;
    float y5 = step(cg + 5, qc.y, xq5); float e5 = err;
    float y6 = step(cg + 6, qd.x, xq6); float e6 = err;
    float y7 = step(cg + 7, qd.y, xq7); float e7 = err;

    if ((unsigned)(cg + 0) < 511u) *(float2*)(yrow + cg + 0) = make_float2(y0, y1);
    if ((unsigned)(cg + 2) < 511u) *(float2*)(yrow + cg + 2) = make_float2(y2, y3);
    if ((unsigned)(cg + 4) < 511u) *(float2*)(yrow + cg + 4) = make_float2(y4, y5);
    if ((unsigned)(cg + 6) < 511u) *(float2*)(yrow + cg + 6) = make_float2(y6, y7);

    if (l63) {
      float* bw = bufW + (cg + 129);
      bw[0] = e0; bw[1] = e1; bw[2] = e2; bw[3] = e3;
      bw[4] = e4; bw[5] = e5; bw[6] = e6; bw[7] = e7;
    }

    xq0 = w0; xq1 = w1; xq2 = w2; xq3 = w3;
    xq4 = w4; xq5 = w5; xq6 = w6; xq7 = w7;
    pA0 = pB0; pA1 = pB1; pA2 = pB2; pA3 = pB3;
    pB0 = n0;  pB1 = n1;  pB2 = n2;  pB3 = n3;
    qa = fa; qb = fb; qc = fc; qd = fd;
    fa = h0; fb = h1; fc = h2; fd = h3;
  };

  for (int j = 0; j < NCH; ++j) {
    if (wave) {
      int need = j + LAG; if (need > NCH) need = NCH;
      while (__hip_atomic_load(&flags[wave - 1], __ATOMIC_RELAXED,
                               __HIP_MEMORY_SCOPE_WORKGROUP) < need)
        __builtin_amdgcn_s_sleep(1);
      __asm__ volatile("s_waitcnt lgkmcnt(0)" ::: "memory");
    }
    iter8(16 * j);
    iter8(16 * j + 8);
    if (l63) {
      __asm__ volatile("s_waitcnt lgkmcnt(0)" ::: "memory");
      __hip_atomic_store(&flags[wave], j + 1, __ATOMIC_RELAXED,
                         __HIP_MEMORY_SCOPE_WORKGROUP);
    }
  }
}

extern "C" void kernel_launch(void* const* d_in, const int* in_sizes, int n_in,
                              void* d_out, int out_size, void* d_ws, size_t ws_size,
                              hipStream_t stream) {
  const float* x = (const float*)d_in[0];
  float*       y = (float*)d_out;
  if (ws_size >= WS_NEED) {
    unsigned long long* yb = (unsigned long long*)d_ws;         // 3.93 MB + pad
    float* xp = (float*)((char*)d_ws + XP_OFF);
    pack_kernel<<<dim3(NIMG, NW, 8), dim3(256), 0, stream>>>(x, xp);
    dither_packed<<<dim3(NIMG), dim3(512), 0, stream>>>(xp, (uint2*)yb);
    unpack_kernel<<<dim3(NIMG, NW), dim3(256), 0, stream>>>(yb, y);
  } else {
    dither_direct<<<dim3(NIMG), dim3(512), 0, stream>>>(x, y);
  }
}